// Round 4
// baseline (161.079 us; speedup 1.0000x reference)
//
#include <hip/hip_runtime.h>
#include <math.h>

// Problem constants: B=32, C=D=64, H=W=32
#define NPTS 32768      // B*H*W
#define KCB  1024
#define DIM  64
#define HW   1024
#define CHW  65536
#define PT   128        // points per block (k_dist)
#define CTC  256        // codes per LDS chunk
#define NCH  4          // chunks (4*256 = 1024 codes)
#define RWIN 2          // OT band radius (validated R3: absmax 0.0)
#define WSZ  (2*RWIN+1)

__device__ __forceinline__ float block_sum(float v, float* scratch) {
  #pragma unroll
  for (int o = 32; o > 0; o >>= 1) v += __shfl_down(v, o, 64);
  int wid  = threadIdx.x >> 6;
  int lane = threadIdx.x & 63;
  __syncthreads();
  if (lane == 0) scratch[wid] = v;
  __syncthreads();
  float s = 0.f;
  int nw = blockDim.x >> 6;
  for (int w = 0; w < nw; ++w) s += scratch[w];
  return s;
}

// K0: codebook row norms (fmaf chain, bit-identical to R3), zero hist/mse
__global__ __launch_bounds__(256) void k_init(const float* __restrict__ cb,
                                              float* __restrict__ cnorm,
                                              int* __restrict__ hist,
                                              float* __restrict__ msesum) {
  int k = blockIdx.x * 256 + threadIdx.x;
  if (k < KCB) {
    const float4* c4 = (const float4*)(cb + k * DIM);
    float s = 0.f;
    #pragma unroll
    for (int d = 0; d < DIM/4; ++d) {
      float4 v = c4[d];
      s = fmaf(v.x, v.x, s); s = fmaf(v.y, v.y, s);
      s = fmaf(v.z, v.z, s); s = fmaf(v.w, v.w, s);
    }
    cnorm[k] = s;
    hist[k] = 0;
  }
  if (k == 0) msesum[0] = 0.f;
}

// K1: fused distance GEMM + argmin + gather + straight-through write + hist + mse.
// Grid 256 blocks (1/CU), 256 threads. Thread tile 8 pts x 16 codes (0.75 B/MAC ->
// LDS-pipe floor ~31 us). Codes: 4 chunks of 256 in deinterleaved-f4 LDS layout.
__global__ __launch_bounds__(256, 1) void k_dist(const float* __restrict__ x,
                                                 const float* __restrict__ cb,
                                                 const float* __restrict__ cnorm,
                                                 float* __restrict__ out,
                                                 int* __restrict__ hist,
                                                 float* __restrict__ msesum) {
  __shared__ __align__(16) float lp[DIM][PT];    // 32 KB points, dim-major
  __shared__ __align__(16) float lc[DIM][CTC];   // 64 KB code chunk, dim-major deinterleaved
  __shared__ int   s_bd[PT];
  __shared__ float scratch[4];

  int tid = threadIdx.x;
  int n0  = blockIdx.x * PT;
  int b   = n0 >> 10;
  int hw0 = n0 & 1023;
  const float* xb = x + b * CHW + hw0;

  // stage points: lp[c][p] from x[b][c][hw0+p] (coalesced b128 rows)
  {
    int crow = tid >> 5, p4 = tid & 31;
    #pragma unroll
    for (int i = 0; i < 8; ++i) {
      int c = i * 8 + crow;
      *(float4*)&lp[c][p4 * 4] = *(const float4*)(xb + c * HW + p4 * 4);
    }
  }
  __syncthreads();

  int tx = tid & 15;   // -> 16 codes (deinterleaved groups)
  int ty = tid >> 4;   // -> pts ty*8 .. ty*8+7

  // sumx: same d-ordered fmaf chain as R3 (reads are tx-broadcast, conflict-free)
  float sx[8];
  #pragma unroll
  for (int pp = 0; pp < 8; ++pp) sx[pp] = 0.f;
  #pragma unroll 8
  for (int d = 0; d < DIM; ++d) {
    float4 a0 = *(const float4*)&lp[d][ty * 8];
    float4 a1 = *(const float4*)&lp[d][ty * 8 + 4];
    sx[0] = fmaf(a0.x, a0.x, sx[0]); sx[1] = fmaf(a0.y, a0.y, sx[1]);
    sx[2] = fmaf(a0.z, a0.z, sx[2]); sx[3] = fmaf(a0.w, a0.w, sx[3]);
    sx[4] = fmaf(a1.x, a1.x, sx[4]); sx[5] = fmaf(a1.y, a1.y, sx[5]);
    sx[6] = fmaf(a1.z, a1.z, sx[6]); sx[7] = fmaf(a1.w, a1.w, sx[7]);
  }

  float best[8];
  int   bidx[8];
  #pragma unroll
  for (int pp = 0; pp < 8; ++pp) { best[pp] = 3.4e38f; bidx[pp] = 0; }

  for (int ch = 0; ch < NCH; ++ch) {
    int k0 = ch * CTC;
    __syncthreads();   // protect lc from previous chunk's readers
    // stage codes: thread tid stages row k0+tid; float4 group j=tid>>2, elem e=tid&3
    // stored at f4-slot s(j)=(j&3)*16+(j>>2) so inner reads are 2-way (free)
    {
      const float4* row = (const float4*)(cb + (k0 + tid) * DIM);
      int jj = tid >> 2, e = tid & 3;
      int sl = (((jj & 3) << 4) + (jj >> 2)) << 2;   // float offset of slot
      #pragma unroll
      for (int i = 0; i < 16; ++i) {
        float4 v = row[i];
        int d0 = i * 4;
        lc[d0 + 0][sl + e] = v.x;
        lc[d0 + 1][sl + e] = v.y;
        lc[d0 + 2][sl + e] = v.z;
        lc[d0 + 3][sl + e] = v.w;
      }
    }
    __syncthreads();

    float acc[8][16];
    #pragma unroll
    for (int pp = 0; pp < 8; ++pp)
      #pragma unroll
      for (int cc = 0; cc < 16; ++cc) acc[pp][cc] = 0.f;

    // dot accumulation, d-ordered single fmaf chain per (pt,code) — bitwise == R3/np
    #pragma unroll 4
    for (int d = 0; d < DIM; ++d) {
      float4 a0 = *(const float4*)&lp[d][ty * 8];
      float4 a1 = *(const float4*)&lp[d][ty * 8 + 4];
      float4 b0 = *(const float4*)&lc[d][(tx) << 2];        // codes tx*16+ 0..3
      float4 b1 = *(const float4*)&lc[d][(16 + tx) << 2];   // codes tx*16+ 4..7
      float4 b2 = *(const float4*)&lc[d][(32 + tx) << 2];   // codes tx*16+ 8..11
      float4 b3 = *(const float4*)&lc[d][(48 + tx) << 2];   // codes tx*16+12..15
      float av[8]  = {a0.x, a0.y, a0.z, a0.w, a1.x, a1.y, a1.z, a1.w};
      float bv[16] = {b0.x, b0.y, b0.z, b0.w, b1.x, b1.y, b1.z, b1.w,
                      b2.x, b2.y, b2.z, b2.w, b3.x, b3.y, b3.z, b3.w};
      #pragma unroll
      for (int pp = 0; pp < 8; ++pp) {
        float a = av[pp];
        #pragma unroll
        for (int cc = 0; cc < 16; ++cc)
          acc[pp][cc] = fmaf(a, bv[cc], acc[pp][cc]);
      }
    }

    // fold chunk into running argmin (k ascending: chunks asc, cc asc -> first-min)
    const float4* cn4 = (const float4*)(cnorm + k0 + tx * 16);
    float4 c0 = cn4[0], c1 = cn4[1], c2 = cn4[2], c3 = cn4[3];
    float cn[16] = {c0.x, c0.y, c0.z, c0.w, c1.x, c1.y, c1.z, c1.w,
                    c2.x, c2.y, c2.z, c2.w, c3.x, c3.y, c3.z, c3.w};
    #pragma unroll
    for (int pp = 0; pp < 8; ++pp) {
      #pragma unroll
      for (int cc = 0; cc < 16; ++cc) {
        // reference fp32 rounding: (||x||^2 + ||c||^2) - 2*x.c
        float dist = (sx[pp] + cn[cc]) - 2.0f * acc[pp][cc];
        if (dist < best[pp]) { best[pp] = dist; bidx[pp] = k0 + tx * 16 + cc; }
      }
    }
  }

  // cross-tx argmin: packed (distbits<<32|idx), min => min dist, tie -> lower idx
  #pragma unroll
  for (int pp = 0; pp < 8; ++pp) {
    unsigned long long pk =
        ((unsigned long long)__float_as_uint(best[pp]) << 32) | (unsigned)bidx[pp];
    #pragma unroll
    for (int m = 1; m < 16; m <<= 1) {
      unsigned long long o = __shfl_xor(pk, m, 64);
      pk = (o < pk) ? o : pk;
    }
    if (tx == 0) {
      int bi = (int)(pk & 0xffffffffull);
      s_bd[ty * 8 + pp] = bi;
      atomicAdd(&hist[bi], 1);
    }
  }
  __syncthreads();

  // epilogue: gather codebook rows, straight-through write, mse
  {
    int p  = tid & 127;
    int c0 = (tid >> 7) * 32;
    int bd = s_bd[p];
    const float* crow = cb + bd * DIM;
    float* ob = out + b * CHW + hw0;
    float se = 0.f;
    #pragma unroll 8
    for (int cc2 = 0; cc2 < 32; ++cc2) {
      int c = c0 + cc2;
      float xv   = lp[c][p];          // bit-identical copy of x
      float diff = crow[c] - xv;      // nq - x
      se += diff * diff;              // (clean_q - flat)^2
      ob[c * HW + p] = xv + diff;     // x + stop_grad(nq - x), ref rounding
    }
    float tot = block_sum(se, scratch);
    if (tid == 0) atomicAdd(msesum, tot);
  }
}

// K2: fused prep + banded OT dual ascent (full width, 1 block x 1024) + scalars.
// prep block_sum sequence bit-identical to R3's k_prep.
__global__ __launch_bounds__(1024) void k_ot(const int* __restrict__ hist,
                                             const float* __restrict__ msesum,
                                             float* __restrict__ out) {
  __shared__ float s_lt[KCB + 2*RWIN], s_src[KCB + 2*RWIN],
                   s_phi[KCB + 2*RWIN], s_lse[KCB + 2*RWIN];
  __shared__ float scratch[16];
  int i = threadIdx.x;
  int sl = i + RWIN;
  float fi = (float)i;

  float zz = (fi - 511.5f) / (1024.0f / 6.0f);
  float t  = expf(-0.5f * zz * zz);
  float St = block_sum(t, scratch);
  float tgt0 = t / fmaxf(St, 1e-12f);
  float tgtc = fmaxf(tgt0, 1e-12f);
  float St2  = block_sum(tgtc, scratch);
  float tgtw = tgtc / St2;
  float ltw  = logf(fmaxf(tgtw, 1e-12f));

  float h  = (float)hist[i] * (1.0f / 32768.0f);
  float m1 = fmaxf(h, 1e-12f);
  float S1 = block_sum(m1, scratch);
  float cw = m1 / S1;
  float m2 = fmaxf(cw, 1e-12f);
  float S2 = block_sum(m2, scratch);
  float srcw = m2 / S2;

  float pterm = h * logf(h + 1e-10f);
  float ent   = block_sum(pterm, scratch);

  s_lt[sl] = ltw; s_src[sl] = srcw; s_phi[sl] = 0.f; s_lse[sl] = 0.f;
  // pads: inert (exp args flush below fp32 eps of row max — validated R3)
  if (i < RWIN) { s_lt[i] = -100.f; s_src[i] = 0.f; s_phi[i] = 0.f; s_lse[i] = 0.f; }
  if (i >= KCB - RWIN) {
    int p = i + 2*RWIN;
    s_lt[p] = -100.f; s_src[p] = 0.f; s_phi[p] = 0.f; s_lse[p] = 0.f;
  }
  __syncthreads();

  float phi = 0.f, lse = 0.f;
  for (int it = 0; it <= 10; ++it) {
    // Phase A: lse_i = logsumexp_j over band of [lt_j + 20*(phi_j - |i-j|)]
    float m = -3.0e38f;
    float vv[WSZ];
    #pragma unroll
    for (int q = 0; q < WSZ; ++q) {
      float a = s_lt[i + q] + (s_phi[i + q] - fabsf((float)(q - RWIN))) * 20.0f;
      vv[q] = a;
      m = fmaxf(m, a);
    }
    float ssum = 0.f;
    #pragma unroll
    for (int q = 0; q < WSZ; ++q) ssum += expf(vv[q] - m);
    lse = m + logf(ssum);
    s_lse[sl] = lse;
    __syncthreads();
    if (it == 10) break;

    // Phase B: cs_j = sum_r src_r * exp(lt_j + 20*phi_j - 20|j-r| - lse_r)
    float basej = ltw + phi * 20.0f;
    float cs = 0.f;
    #pragma unroll
    for (int q = 0; q < WSZ; ++q) {
      float a = basej - fabsf((float)(q - RWIN)) * 20.0f;
      cs += s_src[i + q] * expf(a - s_lse[i + q]);
    }
    phi += 0.5f * (tgtw - cs);
    s_phi[sl] = phi;
    __syncthreads();
  }

  float term = srcw * (-0.05f * lse) + tgtw * phi;
  float ot   = block_sum(term, scratch);

  if (i == 0) {
    float mse = msesum[0] * (1.0f / 2097152.0f);   // N*D
    out[2097152] = 1.25f * mse + ot;               // codebook + 0.25*commit + ot
    out[2097153] = expf(-ent);                     // perplexity
  }
}

extern "C" void kernel_launch(void* const* d_in, const int* in_sizes, int n_in,
                              void* d_out, int out_size, void* d_ws, size_t ws_size,
                              hipStream_t stream) {
  const float* x  = (const float*)d_in[0];   // [32,64,32,32]
  const float* cb = (const float*)d_in[1];   // [1024,64]
  float* out = (float*)d_out;                // quantized(2097152) | loss | perplexity

  float* cnorm  = (float*)d_ws;                       // 4 KB
  int*   hist   = (int*)((char*)d_ws + 4096);         // 4 KB
  float* msesum = (float*)((char*)d_ws + 8192);       // 4 B

  k_init<<<4, 256, 0, stream>>>(cb, cnorm, hist, msesum);
  k_dist<<<NPTS / PT, 256, 0, stream>>>(x, cb, cnorm, out, hist, msesum);
  k_ot<<<1, 1024, 0, stream>>>(hist, msesum, out);
}